// Round 1
// baseline (25332.588 us; speedup 1.0000x reference)
//
#include <hip/hip_runtime.h>
#include <hip/hip_bf16.h>
#include <cstdint>

// Problem constants
#define SEQ   4096
#define EDIM  1024
#define HDIM  1024
#define G4H   4096   // 4*H
#define NBLK  64     // persistent LSTM blocks

typedef __attribute__((ext_vector_type(8))) short short8;
typedef __attribute__((ext_vector_type(4))) float f32x4;

__device__ inline unsigned short f2bf(float f) {
    __bf16 b = (__bf16)f;
    return __builtin_bit_cast(unsigned short, b);
}

// ---------------- conversion / prep kernels ----------------

__global__ __launch_bounds__(256) void conv_wih(const float* __restrict__ w,
                                                unsigned short* __restrict__ o) {
    size_t i = ((size_t)blockIdx.x * 256 + threadIdx.x) * 4;   // 4M elems total
    float4 v = *reinterpret_cast<const float4*>(w + i);
    ushort4 u;
    u.x = f2bf(v.x); u.y = f2bf(v.y); u.z = f2bf(v.z); u.w = f2bf(v.w);
    *reinterpret_cast<ushort4*>(o + i) = u;
}

__global__ __launch_bounds__(256) void gather_x(const int* __restrict__ sent,
                                                const float* __restrict__ emb,
                                                unsigned short* __restrict__ xo) {
    int s = blockIdx.x;
    int idx = sent[s];
    int i = threadIdx.x * 4;
    float4 v = *reinterpret_cast<const float4*>(emb + (size_t)idx * EDIM + i);
    ushort4 u;
    u.x = f2bf(v.x); u.y = f2bf(v.y); u.z = f2bf(v.z); u.w = f2bf(v.w);
    *reinterpret_cast<ushort4*>(xo + (size_t)s * EDIM + i) = u;
}

// w_eff[h] = sum_t W_hyb[t] * W_tag[t,h]; w_eff[1024] = sum_t W_hyb[t]*b_tag[t] + b_hyb
__global__ __launch_bounds__(256) void weff_kernel(const float* __restrict__ wtag,
                                                   const float* __restrict__ btag,
                                                   const float* __restrict__ whyb,
                                                   const float* __restrict__ bhyb,
                                                   float* __restrict__ weff) {
    if (blockIdx.x < 4) {
        int hcol = blockIdx.x * 256 + threadIdx.x;
        float acc = 0.f;
        #pragma unroll 8
        for (int t = 0; t < 1024; ++t)
            acc += whyb[t] * wtag[(size_t)t * HDIM + hcol];
        weff[hcol] = acc;
    } else {
        __shared__ float red[256];
        float acc = 0.f;
        for (int t = threadIdx.x; t < 1024; t += 256) acc += whyb[t] * btag[t];
        red[threadIdx.x] = acc;
        __syncthreads();
        for (int s2 = 128; s2 > 0; s2 >>= 1) {
            if ((int)threadIdx.x < s2) red[threadIdx.x] += red[threadIdx.x + s2];
            __syncthreads();
        }
        if (threadIdx.x == 0) weff[1024] = red[0] + bhyb[0];
    }
}

// ---------------- x_gates GEMM: xg[S,4H] = xbf @ wihbf^T + (b_ih+b_hh) ----------------
// 128x128 tile, BK=64, 4 waves (2x2), 16x16x32 bf16 MFMA.

__global__ __launch_bounds__(256) void gemm_xgates(const unsigned short* __restrict__ xbf,
                                                   const unsigned short* __restrict__ wihbf,
                                                   const float* __restrict__ b_ih,
                                                   const float* __restrict__ b_hh,
                                                   float* __restrict__ xg) {
    __shared__ short A_l[128 * 64];
    __shared__ short B_l[128 * 64];
    const int tid  = threadIdx.x;
    const int lane = tid & 63;
    const int wid  = tid >> 6;
    const int wm = wid >> 1, wn = wid & 1;
    const int bm = blockIdx.x * 128, bn = blockIdx.y * 128;

    f32x4 acc[4][4];
    #pragma unroll
    for (int mt = 0; mt < 4; ++mt)
        #pragma unroll
        for (int nt = 0; nt < 4; ++nt) {
            f32x4 z = {0.f, 0.f, 0.f, 0.f};
            acc[mt][nt] = z;
        }

    for (int ks = 0; ks < EDIM / 64; ++ks) {
        uint4 ta[4], tb[4];
        #pragma unroll
        for (int r = 0; r < 4; ++r) {
            int lin = r * 256 + tid;      // 16B-chunk id, 1024 chunks per operand tile
            int row = lin >> 3;           // 0..127
            int kc  = lin & 7;            // 0..7 (8 bf16 each)
            const unsigned short* ga = xbf   + (size_t)(bm + row) * EDIM + ks * 64 + kc * 8;
            const unsigned short* gb = wihbf + (size_t)(bn + row) * EDIM + ks * 64 + kc * 8;
            ta[r] = *reinterpret_cast<const uint4*>(ga);
            tb[r] = *reinterpret_cast<const uint4*>(gb);
        }
        __syncthreads();   // previous iteration's reads complete
        #pragma unroll
        for (int r = 0; r < 4; ++r) {
            int lin = r * 256 + tid;
            *reinterpret_cast<uint4*>(&A_l[lin * 8]) = ta[r];
            *reinterpret_cast<uint4*>(&B_l[lin * 8]) = tb[r];
        }
        __syncthreads();
        #pragma unroll
        for (int kk = 0; kk < 2; ++kk) {
            short8 af[4], bfr[4];
            #pragma unroll
            for (int mt = 0; mt < 4; ++mt) {
                int row = wm * 64 + mt * 16 + (lane & 15);
                af[mt] = *reinterpret_cast<const short8*>(&A_l[row * 64 + kk * 32 + (lane >> 4) * 8]);
            }
            #pragma unroll
            for (int nt = 0; nt < 4; ++nt) {
                int row = wn * 64 + nt * 16 + (lane & 15);
                bfr[nt] = *reinterpret_cast<const short8*>(&B_l[row * 64 + kk * 32 + (lane >> 4) * 8]);
            }
            #pragma unroll
            for (int mt = 0; mt < 4; ++mt)
                #pragma unroll
                for (int nt = 0; nt < 4; ++nt)
                    acc[mt][nt] = __builtin_amdgcn_mfma_f32_16x16x32_bf16(af[mt], bfr[nt], acc[mt][nt], 0, 0, 0);
        }
    }
    // epilogue: C/D layout col=lane&15, row=(lane>>4)*4+reg  [m89-verified]
    #pragma unroll
    for (int nt = 0; nt < 4; ++nt) {
        int gn = bn + wn * 64 + nt * 16 + (lane & 15);
        float bias = b_ih[gn] + b_hh[gn];
        #pragma unroll
        for (int mt = 0; mt < 4; ++mt) {
            int gm0 = bm + wm * 64 + mt * 16 + (lane >> 4) * 4;
            #pragma unroll
            for (int r = 0; r < 4; ++r)
                xg[(size_t)(gm0 + r) * G4H + gn] = acc[mt][nt][r] + bias;
        }
    }
}

// ---------------- persistent LSTM recurrence ----------------
// 64 blocks x 1024 threads. Block b owns hidden slice j in [b*16, b*16+16) and the
// 64 rows {gate*1024 + b*16 + j}. Each thread holds 64 fp32 W_hh weights in VGPRs:
// thread (rowgrp=tid>>6, lane=tid&63) covers rows rl=rowgrp*4+rr, columns
// {q*256 + lane*4 + e : q<4, e<4}  (float4-friendly both for weight load and LDS h read).

__global__ __launch_bounds__(1024, 4) void lstm_seq(const float* __restrict__ xg,
                                                    const float* __restrict__ whh,
                                                    float* __restrict__ hbuf,   // 2*1024 f32, zeroed
                                                    float* __restrict__ hs,     // SEQ*1024 f32
                                                    unsigned* __restrict__ bar) // [0]=cnt, [16]=epoch, zeroed
{
    const int tid    = threadIdx.x;
    const int b      = blockIdx.x;
    const int lane   = tid & 63;
    const int rowgrp = tid >> 6;     // == wave id, 0..15

    __shared__ float hlds[1024];
    __shared__ float gsm[64];
    __shared__ float xgs[64];

    // load W_hh fragment into registers
    float4 w[4][4];
    #pragma unroll
    for (int rr = 0; rr < 4; ++rr) {
        int rl   = rowgrp * 4 + rr;
        int grow = ((rl >> 4) << 10) + (b << 4) + (rl & 15);
        #pragma unroll
        for (int q = 0; q < 4; ++q)
            w[rr][q] = *reinterpret_cast<const float4*>(whh + (size_t)grow * HDIM + q * 256 + lane * 4);
    }

    float c = 0.f;

    for (int t = 0; t < SEQ; ++t) {
        const float* hread  = hbuf + (t & 1) * HDIM;
        float*       hwrite = hbuf + ((t + 1) & 1) * HDIM;

        // stage h (4KB) and this step's xg slice into LDS
        if (tid < 256)
            *reinterpret_cast<float4*>(&hlds[tid * 4]) =
                *reinterpret_cast<const float4*>(hread + tid * 4);
        if (tid < 64) {
            int grow = ((tid >> 4) << 10) + (b << 4) + (tid & 15);
            xgs[tid] = xg[(size_t)t * G4H + grow];
        }
        __syncthreads();

        float p0 = 0.f, p1 = 0.f, p2 = 0.f, p3 = 0.f;
        #pragma unroll
        for (int q = 0; q < 4; ++q) {
            float4 h4 = *reinterpret_cast<const float4*>(&hlds[q * 256 + lane * 4]);
            p0 += w[0][q].x * h4.x + w[0][q].y * h4.y + w[0][q].z * h4.z + w[0][q].w * h4.w;
            p1 += w[1][q].x * h4.x + w[1][q].y * h4.y + w[1][q].z * h4.z + w[1][q].w * h4.w;
            p2 += w[2][q].x * h4.x + w[2][q].y * h4.y + w[2][q].z * h4.z + w[2][q].w * h4.w;
            p3 += w[3][q].x * h4.x + w[3][q].y * h4.y + w[3][q].z * h4.z + w[3][q].w * h4.w;
        }
        #pragma unroll
        for (int m = 1; m < 64; m <<= 1) {
            p0 += __shfl_xor(p0, m);
            p1 += __shfl_xor(p1, m);
            p2 += __shfl_xor(p2, m);
            p3 += __shfl_xor(p3, m);
        }
        if (lane == 0) {
            gsm[rowgrp * 4 + 0] = p0 + xgs[rowgrp * 4 + 0];
            gsm[rowgrp * 4 + 1] = p1 + xgs[rowgrp * 4 + 1];
            gsm[rowgrp * 4 + 2] = p2 + xgs[rowgrp * 4 + 2];
            gsm[rowgrp * 4 + 3] = p3 + xgs[rowgrp * 4 + 3];
        }
        __syncthreads();

        if (tid < 16) {
            float iv = 1.f / (1.f + __expf(-gsm[tid]));
            float fv = 1.f / (1.f + __expf(-gsm[16 + tid]));
            float gv = tanhf(gsm[32 + tid]);
            float ov = 1.f / (1.f + __expf(-gsm[48 + tid]));
            c = fv * c + iv * gv;
            float hn = ov * tanhf(c);
            hwrite[b * 16 + tid] = hn;
            hs[(size_t)t * HDIM + b * 16 + tid] = hn;
        }
        __syncthreads();   // drains vmcnt: h stores of all waves are in cache hierarchy

        if (tid == 0) {
            unsigned old = __hip_atomic_fetch_add(&bar[0], 1u, __ATOMIC_ACQ_REL,
                                                  __HIP_MEMORY_SCOPE_AGENT);
            if (old == (unsigned)(NBLK * (t + 1) - 1)) {
                __hip_atomic_store(&bar[16], (unsigned)(t + 1), __ATOMIC_RELEASE,
                                   __HIP_MEMORY_SCOPE_AGENT);
            } else {
                while (__hip_atomic_load(&bar[16], __ATOMIC_RELAXED,
                                         __HIP_MEMORY_SCOPE_AGENT) < (unsigned)(t + 1)) {}
                (void)__hip_atomic_load(&bar[16], __ATOMIC_ACQUIRE, __HIP_MEMORY_SCOPE_AGENT);
            }
        }
        __syncthreads();
    }
}

// ---------------- output head: out[s] = sigmoid(dot(w_eff, hs[s]) + bias_eff) ----------------

__global__ __launch_bounds__(256) void out_head(const float* __restrict__ hs,
                                                const float* __restrict__ weff,
                                                float* __restrict__ out) {
    int wid = threadIdx.x >> 6, lane = threadIdx.x & 63;
    int s = blockIdx.x * 4 + wid;
    const float* h = hs + (size_t)s * HDIM;
    float sum = 0.f;
    #pragma unroll
    for (int i = 0; i < 4; ++i) {
        float4 hv = *reinterpret_cast<const float4*>(h + i * 256 + lane * 4);
        float4 wv = *reinterpret_cast<const float4*>(weff + i * 256 + lane * 4);
        sum += hv.x * wv.x + hv.y * wv.y + hv.z * wv.z + hv.w * wv.w;
    }
    #pragma unroll
    for (int m = 1; m < 64; m <<= 1) sum += __shfl_xor(sum, m);
    if (lane == 0) out[s] = 1.f / (1.f + __expf(-(sum + weff[1024])));
}

// ---------------- launch ----------------

extern "C" void kernel_launch(void* const* d_in, const int* in_sizes, int n_in,
                              void* d_out, int out_size, void* d_ws, size_t ws_size,
                              hipStream_t stream) {
    const int*   sent = (const int*)d_in[0];
    const float* emb  = (const float*)d_in[1];
    const float* wih  = (const float*)d_in[2];
    const float* whh  = (const float*)d_in[3];
    const float* bih  = (const float*)d_in[4];
    const float* bhh  = (const float*)d_in[5];
    const float* wtag = (const float*)d_in[6];
    const float* btag = (const float*)d_in[7];
    const float* whyb = (const float*)d_in[8];
    const float* bhyb = (const float*)d_in[9];
    float* out = (float*)d_out;

    char* ws = (char*)d_ws;
    float*          xg    = (float*)(ws);                              // 64 MB
    float*          hs    = (float*)(ws + ((size_t)64 << 20));         // 16 MB
    unsigned short* xbf   = (unsigned short*)(ws + ((size_t)80 << 20)); // 8 MB
    unsigned short* wihbf = (unsigned short*)(ws + ((size_t)88 << 20)); // 8 MB
    float*          weff  = (float*)(ws + ((size_t)96 << 20));          // 1025 f32
    float*          hbuf  = (float*)(ws + ((size_t)96 << 20) + 8192);   // 2048 f32
    unsigned*       bar   = (unsigned*)(ws + ((size_t)96 << 20) + 16384);

    (void)hipMemsetAsync(hbuf, 0, 2048 * sizeof(float), stream);
    (void)hipMemsetAsync(bar, 0, 256, stream);

    conv_wih<<<4096, 256, 0, stream>>>(wih, wihbf);
    gather_x<<<4096, 256, 0, stream>>>(sent, emb, xbf);
    weff_kernel<<<5, 256, 0, stream>>>(wtag, btag, whyb, bhyb, weff);

    dim3 gg(32, 32);
    gemm_xgates<<<gg, 256, 0, stream>>>(xbf, wihbf, bih, bhh, xg);

    void* args[] = { (void*)&xg, (void*)&whh, (void*)&hbuf, (void*)&hs, (void*)&bar };
    (void)hipLaunchCooperativeKernel((const void*)lstm_seq, dim3(NBLK), dim3(1024),
                                     args, 0, stream);

    out_head<<<1024, 256, 0, stream>>>(hs, weff, out);
}

// Round 2
// 11335.896 us; speedup vs baseline: 2.2347x; 2.2347x over previous
//
#include <hip/hip_runtime.h>
#include <hip/hip_bf16.h>
#include <cstdint>

// Problem constants
#define SEQ   4096
#define EDIM  1024
#define HDIM  1024
#define G4H   4096   // 4*H
#define NBLK  64     // persistent LSTM blocks

typedef __attribute__((ext_vector_type(8))) short short8;
typedef __attribute__((ext_vector_type(4))) float f32x4;

__device__ inline unsigned short f2bf(float f) {
    __bf16 b = (__bf16)f;
    return __builtin_bit_cast(unsigned short, b);
}

// ---------------- conversion / prep kernels ----------------

__global__ __launch_bounds__(256) void conv_wih(const float* __restrict__ w,
                                                unsigned short* __restrict__ o) {
    size_t i = ((size_t)blockIdx.x * 256 + threadIdx.x) * 4;   // 4M elems total
    float4 v = *reinterpret_cast<const float4*>(w + i);
    ushort4 u;
    u.x = f2bf(v.x); u.y = f2bf(v.y); u.z = f2bf(v.z); u.w = f2bf(v.w);
    *reinterpret_cast<ushort4*>(o + i) = u;
}

__global__ __launch_bounds__(256) void gather_x(const int* __restrict__ sent,
                                                const float* __restrict__ emb,
                                                unsigned short* __restrict__ xo) {
    int s = blockIdx.x;
    int idx = sent[s];
    int i = threadIdx.x * 4;
    float4 v = *reinterpret_cast<const float4*>(emb + (size_t)idx * EDIM + i);
    ushort4 u;
    u.x = f2bf(v.x); u.y = f2bf(v.y); u.z = f2bf(v.z); u.w = f2bf(v.w);
    *reinterpret_cast<ushort4*>(xo + (size_t)s * EDIM + i) = u;
}

// w_eff[h] = sum_t W_hyb[t] * W_tag[t,h]; w_eff[1024] = sum_t W_hyb[t]*b_tag[t] + b_hyb
__global__ __launch_bounds__(256) void weff_kernel(const float* __restrict__ wtag,
                                                   const float* __restrict__ btag,
                                                   const float* __restrict__ whyb,
                                                   const float* __restrict__ bhyb,
                                                   float* __restrict__ weff) {
    if (blockIdx.x < 4) {
        int hcol = blockIdx.x * 256 + threadIdx.x;
        float acc = 0.f;
        #pragma unroll 8
        for (int t = 0; t < 1024; ++t)
            acc += whyb[t] * wtag[(size_t)t * HDIM + hcol];
        weff[hcol] = acc;
    } else {
        __shared__ float red[256];
        float acc = 0.f;
        for (int t = threadIdx.x; t < 1024; t += 256) acc += whyb[t] * btag[t];
        red[threadIdx.x] = acc;
        __syncthreads();
        for (int s2 = 128; s2 > 0; s2 >>= 1) {
            if ((int)threadIdx.x < s2) red[threadIdx.x] += red[threadIdx.x + s2];
            __syncthreads();
        }
        if (threadIdx.x == 0) weff[1024] = red[0] + bhyb[0];
    }
}

// ---------------- x_gates GEMM: xg[S,4H] = xbf @ wihbf^T + (b_ih+b_hh) ----------------
// 128x128 tile, BK=64, 4 waves (2x2), 16x16x32 bf16 MFMA.

__global__ __launch_bounds__(256) void gemm_xgates(const unsigned short* __restrict__ xbf,
                                                   const unsigned short* __restrict__ wihbf,
                                                   const float* __restrict__ b_ih,
                                                   const float* __restrict__ b_hh,
                                                   float* __restrict__ xg) {
    __shared__ short A_l[128 * 64];
    __shared__ short B_l[128 * 64];
    const int tid  = threadIdx.x;
    const int lane = tid & 63;
    const int wid  = tid >> 6;
    const int wm = wid >> 1, wn = wid & 1;
    const int bm = blockIdx.x * 128, bn = blockIdx.y * 128;

    f32x4 acc[4][4];
    #pragma unroll
    for (int mt = 0; mt < 4; ++mt)
        #pragma unroll
        for (int nt = 0; nt < 4; ++nt) {
            f32x4 z = {0.f, 0.f, 0.f, 0.f};
            acc[mt][nt] = z;
        }

    for (int ks = 0; ks < EDIM / 64; ++ks) {
        uint4 ta[4], tb[4];
        #pragma unroll
        for (int r = 0; r < 4; ++r) {
            int lin = r * 256 + tid;      // 16B-chunk id, 1024 chunks per operand tile
            int row = lin >> 3;           // 0..127
            int kc  = lin & 7;            // 0..7 (8 bf16 each)
            const unsigned short* ga = xbf   + (size_t)(bm + row) * EDIM + ks * 64 + kc * 8;
            const unsigned short* gb = wihbf + (size_t)(bn + row) * EDIM + ks * 64 + kc * 8;
            ta[r] = *reinterpret_cast<const uint4*>(ga);
            tb[r] = *reinterpret_cast<const uint4*>(gb);
        }
        __syncthreads();   // previous iteration's reads complete
        #pragma unroll
        for (int r = 0; r < 4; ++r) {
            int lin = r * 256 + tid;
            *reinterpret_cast<uint4*>(&A_l[lin * 8]) = ta[r];
            *reinterpret_cast<uint4*>(&B_l[lin * 8]) = tb[r];
        }
        __syncthreads();
        #pragma unroll
        for (int kk = 0; kk < 2; ++kk) {
            short8 af[4], bfr[4];
            #pragma unroll
            for (int mt = 0; mt < 4; ++mt) {
                int row = wm * 64 + mt * 16 + (lane & 15);
                af[mt] = *reinterpret_cast<const short8*>(&A_l[row * 64 + kk * 32 + (lane >> 4) * 8]);
            }
            #pragma unroll
            for (int nt = 0; nt < 4; ++nt) {
                int row = wn * 64 + nt * 16 + (lane & 15);
                bfr[nt] = *reinterpret_cast<const short8*>(&B_l[row * 64 + kk * 32 + (lane >> 4) * 8]);
            }
            #pragma unroll
            for (int mt = 0; mt < 4; ++mt)
                #pragma unroll
                for (int nt = 0; nt < 4; ++nt)
                    acc[mt][nt] = __builtin_amdgcn_mfma_f32_16x16x32_bf16(af[mt], bfr[nt], acc[mt][nt], 0, 0, 0);
        }
    }
    // epilogue: C/D layout col=lane&15, row=(lane>>4)*4+reg  [m89-verified]
    #pragma unroll
    for (int nt = 0; nt < 4; ++nt) {
        int gn = bn + wn * 64 + nt * 16 + (lane & 15);
        float bias = b_ih[gn] + b_hh[gn];
        #pragma unroll
        for (int mt = 0; mt < 4; ++mt) {
            int gm0 = bm + wm * 64 + mt * 16 + (lane >> 4) * 4;
            #pragma unroll
            for (int r = 0; r < 4; ++r)
                xg[(size_t)(gm0 + r) * G4H + gn] = acc[mt][nt][r] + bias;
        }
    }
}

// ---------------- persistent LSTM recurrence ----------------
// 64 blocks x 512 threads (8 waves, 2 waves/SIMD -> VGPR cap 256).
// Block b owns hidden units [b*16, b*16+16) => gate rows {g*1024 + b*16 + j}.
// Thread (wave wv, lane l) holds 8 rows x 16 cols of W_hh in registers:
//   rows rl = wv*8+rr (rr<8), global row = (rl>>4)*1024 + b*16 + (rl&15)
//   cols l*16 + q*4 + e (q<4, e<4)  -> w[8][4] float4 = 128 VGPRs.
// h exchange: tagged 8-byte atomics {tag=t, h} in hglob[2][1024], parity-buffered.
// The tag and value travel in ONE atomic word -> no fences, one L3 round trip.
// Safety: buffer (t&1) can only be overwritten (with h(t+2)) after ALL blocks
// published tag t+1, which post-dates every block's step-t reads (B2 + program
// order in wave 0 guarantee publish follows all own-block reads).

__global__ __launch_bounds__(512, 2) void lstm_seq(const float* __restrict__ xg,
                                                   const float* __restrict__ whh,
                                                   unsigned long long* __restrict__ hglob, // [2][1024] tagged, zeroed
                                                   float* __restrict__ hs)                 // SEQ*1024 f32
{
    const int tid  = threadIdx.x;
    const int b    = blockIdx.x;
    const int lane = tid & 63;
    const int wv   = tid >> 6;   // 0..7

    __shared__ float hlds[1024];
    __shared__ float gsm[64];
    __shared__ float xgs[2][64];

    // register-resident W_hh fragment
    float4 w[8][4];
    #pragma unroll
    for (int rr = 0; rr < 8; ++rr) {
        int rl = wv * 8 + rr;
        int grow = ((rl >> 4) << 10) + (b << 4) + (rl & 15);
        #pragma unroll
        for (int q = 0; q < 4; ++q)
            w[rr][q] = *reinterpret_cast<const float4*>(whh + (size_t)grow * HDIM + lane * 16 + q * 4);
    }

    // prologue: wave 1 preloads xg(0) slice
    if (wv == 1) {
        int grow = ((lane >> 4) << 10) + (b << 4) + (lane & 15);
        xgs[0][lane] = xg[grow];
    }

    float c = 0.f;

    for (int t = 0; t < SEQ; ++t) {
        if (wv == 0) {
            // poll tagged h(t): lane l owns slots {l + 64*i}, coalesced 512B per instr
            const unsigned long long* src = hglob + (size_t)(t & 1) * HDIM;
            unsigned long long u[16];
            for (;;) {
                bool ok = true;
                #pragma unroll
                for (int i = 0; i < 16; ++i) {
                    u[i] = __hip_atomic_load(src + i * 64 + lane, __ATOMIC_RELAXED,
                                             __HIP_MEMORY_SCOPE_AGENT);
                    ok &= ((unsigned)(u[i] >> 32) >= (unsigned)t);
                }
                if (__all(ok)) break;
            }
            #pragma unroll
            for (int i = 0; i < 16; ++i)
                hlds[i * 64 + lane] = __builtin_bit_cast(float, (unsigned)(u[i] & 0xffffffffu));
        } else if (wv == 1) {
            if (t + 1 < SEQ) {  // prefetch next step's xg slice (off critical path)
                int grow = ((lane >> 4) << 10) + (b << 4) + (lane & 15);
                xgs[(t + 1) & 1][lane] = xg[(size_t)(t + 1) * G4H + grow];
            }
        }
        __syncthreads();   // B1: h(t) staged in hlds, xg(t) present

        // matvec: 16 h-values reused across 8 rows
        float4 h4[4];
        #pragma unroll
        for (int q = 0; q < 4; ++q)
            h4[q] = *reinterpret_cast<const float4*>(&hlds[lane * 16 + q * 4]);
        float p[8];
        #pragma unroll
        for (int rr = 0; rr < 8; ++rr) {
            float s = 0.f;
            #pragma unroll
            for (int q = 0; q < 4; ++q)
                s += w[rr][q].x * h4[q].x + w[rr][q].y * h4[q].y
                   + w[rr][q].z * h4[q].z + w[rr][q].w * h4[q].w;
            p[rr] = s;
        }
        #pragma unroll
        for (int m = 1; m < 64; m <<= 1) {
            #pragma unroll
            for (int rr = 0; rr < 8; ++rr)
                p[rr] += __shfl_xor(p[rr], m);
        }
        if (lane == 0) {
            #pragma unroll
            for (int rr = 0; rr < 8; ++rr)
                gsm[wv * 8 + rr] = p[rr] + xgs[t & 1][wv * 8 + rr];
        }
        __syncthreads();   // B2: all 64 gate pre-activations in gsm

        if (tid < 16) {
            float gi = gsm[tid], gf = gsm[16 + tid], gg = gsm[32 + tid], go = gsm[48 + tid];
            float iv = 1.f / (1.f + __expf(-gi));
            float fv = 1.f / (1.f + __expf(-gf));
            float e2 = __expf(2.f * gg);
            float gv = (e2 - 1.f) / (e2 + 1.f);
            float ov = 1.f / (1.f + __expf(-go));
            c = fv * c + iv * gv;
            float e2c = __expf(2.f * c);
            float hn = ov * ((e2c - 1.f) / (e2c + 1.f));
            hs[(size_t)t * HDIM + (b << 4) + tid] = hn;
            unsigned long long pk = ((unsigned long long)(unsigned)(t + 1) << 32)
                                  | (unsigned long long)__builtin_bit_cast(unsigned, hn);
            __hip_atomic_store(hglob + (size_t)((t + 1) & 1) * HDIM + (b << 4) + tid, pk,
                               __ATOMIC_RELAXED, __HIP_MEMORY_SCOPE_AGENT);
        }
        // no third barrier needed: next step's B1 + poll gating protect hlds/gsm/xgs
    }
}

// ---------------- output head: out[s] = sigmoid(dot(w_eff, hs[s]) + bias_eff) ----------------

__global__ __launch_bounds__(256) void out_head(const float* __restrict__ hs,
                                                const float* __restrict__ weff,
                                                float* __restrict__ out) {
    int wid = threadIdx.x >> 6, lane = threadIdx.x & 63;
    int s = blockIdx.x * 4 + wid;
    const float* h = hs + (size_t)s * HDIM;
    float sum = 0.f;
    #pragma unroll
    for (int i = 0; i < 4; ++i) {
        float4 hv = *reinterpret_cast<const float4*>(h + i * 256 + lane * 4);
        float4 wv = *reinterpret_cast<const float4*>(weff + i * 256 + lane * 4);
        sum += hv.x * wv.x + hv.y * wv.y + hv.z * wv.z + hv.w * wv.w;
    }
    #pragma unroll
    for (int m = 1; m < 64; m <<= 1) sum += __shfl_xor(sum, m);
    if (lane == 0) out[s] = 1.f / (1.f + __expf(-(sum + weff[1024])));
}

// ---------------- launch ----------------

extern "C" void kernel_launch(void* const* d_in, const int* in_sizes, int n_in,
                              void* d_out, int out_size, void* d_ws, size_t ws_size,
                              hipStream_t stream) {
    const int*   sent = (const int*)d_in[0];
    const float* emb  = (const float*)d_in[1];
    const float* wih  = (const float*)d_in[2];
    const float* whh  = (const float*)d_in[3];
    const float* bih  = (const float*)d_in[4];
    const float* bhh  = (const float*)d_in[5];
    const float* wtag = (const float*)d_in[6];
    const float* btag = (const float*)d_in[7];
    const float* whyb = (const float*)d_in[8];
    const float* bhyb = (const float*)d_in[9];
    float* out = (float*)d_out;

    char* ws = (char*)d_ws;
    float*              xg    = (float*)(ws);                               // 64 MB
    float*              hs    = (float*)(ws + ((size_t)64 << 20));          // 16 MB
    unsigned short*     xbf   = (unsigned short*)(ws + ((size_t)80 << 20)); // 8 MB
    unsigned short*     wihbf = (unsigned short*)(ws + ((size_t)88 << 20)); // 8 MB
    float*              weff  = (float*)(ws + ((size_t)96 << 20));          // 1025 f32
    unsigned long long* hglob = (unsigned long long*)(ws + ((size_t)96 << 20) + 8192); // 16 KB

    (void)hipMemsetAsync(hglob, 0, 2 * HDIM * sizeof(unsigned long long), stream);

    conv_wih<<<4096, 256, 0, stream>>>(wih, wihbf);
    gather_x<<<4096, 256, 0, stream>>>(sent, emb, xbf);
    weff_kernel<<<5, 256, 0, stream>>>(wtag, btag, whyb, bhyb, weff);

    dim3 gg(32, 32);
    gemm_xgates<<<gg, 256, 0, stream>>>(xbf, wihbf, bih, bhh, xg);

    void* args[] = { (void*)&xg, (void*)&whh, (void*)&hglob, (void*)&hs };
    (void)hipLaunchCooperativeKernel((const void*)lstm_seq, dim3(NBLK), dim3(512),
                                     args, 0, stream);

    out_head<<<1024, 256, 0, stream>>>(hs, weff, out);
}